// Round 8
// baseline (885.731 us; speedup 1.0000x reference)
//
#include <hip/hip_runtime.h>
#include <math.h>

// VQ-VAE quantizer, MI355X. N=65536 vectors (B64*H32*W32), D=64, K=1024.
// Round-8: barrier-free MFMA grind.
//  R5/R6/R7 evidence: MfmaUtil pinned ~31% at 4/8/16 waves per CU -> the
//  lockstep {stage, ds_read, MFMA, argmin, vmcnt(0)+barrier} convoy serializes
//  the pipes; occupancy does not help. Fix: codebook splits are 393 KB ->
//  L2-resident; store them in ws PRE-SWIZZLED into MFMA A-fragment order and
//  load per-wave as coalesced 1KB global_load_dwordx4 (no LDS tile, no
//  in-loop barrier). Waves are fully independent: wave w of a block = K-quarter
//  w over the block's 32 vectors; merge via LDS u64 atomicMin (R4-proven).
//  All numerics bit-identical to rounds 5-7 (6-term bf16x3 split dot, dist =
//  fl(fl(zz+cc) - fl(2*dot)), ascending chains, ties -> lower k).
//
// ws layout:
//   float ws_f[0..1024)    cc[k] = |codebook_k|^2
//   uint  ws_u[1024..2048) histogram
//   float ws_f[2048..4096) per-block partial sums (2048 blocks)
//   byte 16384..409600     codebook bf16x3 A-fragments:
//     tile kt=k>>5 (32 codes): KT_BYTES=12288 per tile,
//     addr = kt*12288 + s*4096 + kc*1024 + li*32 + g*16   (li=k&31)
//     16B at (s,kc,li,g) = codes row li, d-range kc*16+g*8..+8, split s
// If ws_size < 409600 -> fallback fp32 kernel (round-3, known-good).

#define OFF_VQLOSS  4194304
#define OFF_COMMIT  4194305
#define OFF_IDX     4194306
#define OFF_USAGE   4259842
#define OFF_PERP    4259843

#define CAF_BYTE_OFF 16384
#define KT_BYTES     12288
#define WS_REQUIRED  (CAF_BYTE_OFF + 32 * KT_BYTES)   // 409,600

typedef __attribute__((ext_vector_type(8)))  short short8;   // 8 bf16 = 4 VGPR
typedef __attribute__((ext_vector_type(16))) float f32x16;

__device__ inline unsigned short f2bf(float x) {             // round-to-nearest-even
    unsigned u = __float_as_uint(x);
    return (unsigned short)((u + 0x7FFFu + ((u >> 16) & 1u)) >> 16);
}
__device__ inline float bf2f(unsigned short h) {
    return __uint_as_float(((unsigned)h) << 16);
}

// ---------------- init: cc, hist zero, codebook bf16x3 A-fragments ----------------
__global__ __launch_bounds__(256) void vq_init(const float* __restrict__ cb,
                                               float* __restrict__ ws_f,
                                               unsigned* __restrict__ ws_u,
                                               char* __restrict__ cafB,
                                               int do_caf) {
    int k = blockIdx.x * 256 + threadIdx.x;    // grid 4x256 -> k in [0,1024)
    ws_u[1024 + k] = 0u;
    const float* row = cb + k * 64;
    float acc = 0.0f;
    #pragma unroll
    for (int d = 0; d < 64; ++d) {
        float v = row[d];
        acc = __fadd_rn(acc, __fmul_rn(v, v));  // ascending chain = rounds 1-7
    }
    ws_f[k] = acc;

    if (!do_caf) return;
    const int kt = k >> 5, li = k & 31;
    #pragma unroll
    for (int q = 0; q < 8; ++q) {              // q = d-octet; kc=q>>1, g=q&1
        unsigned long long u[3][2] = {{0,0},{0,0},{0,0}};
        #pragma unroll
        for (int e = 0; e < 8; ++e) {
            float x = row[q * 8 + e];
            unsigned short h1 = f2bf(x);  float r1 = __fsub_rn(x,  bf2f(h1));
            unsigned short h2 = f2bf(r1); float r2 = __fsub_rn(r1, bf2f(h2));
            unsigned short h3 = f2bf(r2);
            const int hw = e >> 2, sh = 16 * (e & 3);
            u[0][hw] |= ((unsigned long long)h1) << sh;
            u[1][hw] |= ((unsigned long long)h2) << sh;
            u[2][hw] |= ((unsigned long long)h3) << sh;
        }
        const int kc = q >> 1, g = q & 1;
        char* dst = cafB + (size_t)kt * KT_BYTES + kc * 1024 + li * 32 + g * 16;
        #pragma unroll
        for (int s = 0; s < 3; ++s) {
            *reinterpret_cast<unsigned long long*>(dst + s * 4096 + 0) = u[s][0];
            *reinterpret_cast<unsigned long long*>(dst + s * 4096 + 8) = u[s][1];
        }
    }
}

// ---------------- main: barrier-free MFMA grind + argmin + epilogue ----------------
// 2048 blocks x 32 vectors; 4 waves/block, wave grp scans codes
// [grp*256, grp*256+256) with NO inter-wave synchronization in the loop.
__global__ __launch_bounds__(256, 2) void vq_main(const float* __restrict__ ze,
                                                  const float* __restrict__ cb,
                                                  const float* __restrict__ ccg,
                                                  const char* __restrict__ cafB,
                                                  unsigned* __restrict__ hist,
                                                  float* __restrict__ partial,
                                                  float* __restrict__ out) {
    const int t    = threadIdx.x;
    const int grp  = t >> 6;            // wave = K-quarter 0..3
    const int lane = t & 63;
    const int li   = lane & 31;         // MFMA row/col index
    const int g    = lane >> 5;         // half-wave group (d-octet select)
    const int blk  = blockIdx.x;        // 2048 blocks x 32 vectors

    __shared__ unsigned long long best[32];
    if (t < 32) best[t] = ~0ull;

    // ---- load z, compute zz (ascending chain, bit-identical to R1-7),
    //      build resident bf16x3 B-fragments (block's 32 vectors) ----
    const int n    = (blk << 5) + li;
    const size_t zb = ((size_t)(n >> 10) << 16) + (size_t)(n & 1023);
    float zz, bd;
    int   bk;
    short8 zf[3][4];                    // [split][kc]
    {
        float s = 0.0f;
        #pragma unroll
        for (int d = 0; d < 64; ++d) {
            float x = ze[zb + ((size_t)d << 10)];
            s = __fadd_rn(s, __fmul_rn(x, x));
        }
        zz = s; bd = INFINITY; bk = 0;
        #pragma unroll
        for (int kc = 0; kc < 4; ++kc) {
            unsigned long long u[3][2] = {{0,0},{0,0},{0,0}};
            #pragma unroll
            for (int e = 0; e < 8; ++e) {
                int d = kc * 16 + (g << 3) + e;
                float x = ze[zb + ((size_t)d << 10)];    // L1-hot re-read
                unsigned short h1 = f2bf(x);  float r1 = __fsub_rn(x,  bf2f(h1));
                unsigned short h2 = f2bf(r1); float r2 = __fsub_rn(r1, bf2f(h2));
                unsigned short h3 = f2bf(r2);
                const int hw = e >> 2, sh = 16 * (e & 3);
                u[0][hw] |= ((unsigned long long)h1) << sh;
                u[1][hw] |= ((unsigned long long)h2) << sh;
                u[2][hw] |= ((unsigned long long)h3) << sh;
            }
            #pragma unroll
            for (int s2 = 0; s2 < 3; ++s2) {
                union { unsigned long long uu[2]; short8 v; } cvt;
                cvt.uu[0] = u[s2][0]; cvt.uu[1] = u[s2][1];
                zf[s2][kc] = cvt.v;
            }
        }
    }

    __syncthreads();                    // best[] init visible (only barrier pre-merge)

    // ---- 8 k-tiles of 32 codes, fully independent per wave ----
    for (int kt2 = 0; kt2 < 8; ++kt2) {
        const int kt = (grp << 3) + kt2;
        const int k0 = kt << 5;

        // batch 12 coalesced 1KB A-frag loads from L2/L1 (pre-swizzled layout)
        const char* abase = cafB + (size_t)kt * KT_BYTES + li * 32 + g * 16;
        short8 a[4][3];
        #pragma unroll
        for (int kc = 0; kc < 4; ++kc)
            #pragma unroll
            for (int s2 = 0; s2 < 3; ++s2)
                a[kc][s2] = *reinterpret_cast<const short8*>(abase + s2 * 4096 + kc * 1024);

        f32x16 aH, aM, aL;
        #pragma unroll
        for (int r = 0; r < 16; ++r) { aH[r] = 0.0f; aM[r] = 0.0f; aL[r] = 0.0f; }

        #pragma unroll
        for (int kc = 0; kc < 4; ++kc) {
            // 6 terms, 3 independent chains (drop c3z2, c2z3, c3z3) - same as R6/R7
            aL = __builtin_amdgcn_mfma_f32_32x32x16_bf16(a[kc][1], zf[1][kc], aL, 0, 0, 0); // c2 z2
            aL = __builtin_amdgcn_mfma_f32_32x32x16_bf16(a[kc][2], zf[0][kc], aL, 0, 0, 0); // c3 z1
            aL = __builtin_amdgcn_mfma_f32_32x32x16_bf16(a[kc][0], zf[2][kc], aL, 0, 0, 0); // c1 z3
            aM = __builtin_amdgcn_mfma_f32_32x32x16_bf16(a[kc][1], zf[0][kc], aM, 0, 0, 0); // c2 z1
            aM = __builtin_amdgcn_mfma_f32_32x32x16_bf16(a[kc][0], zf[1][kc], aM, 0, 0, 0); // c1 z2
            aH = __builtin_amdgcn_mfma_f32_32x32x16_bf16(a[kc][0], zf[0][kc], aH, 0, 0, 0); // c1 z1
        }
        // dist + running argmin. C/D: col=lane&31 (vector), row=(r&3)+8*(r>>2)+4g
        #pragma unroll
        for (int j = 0; j < 4; ++j) {
            float4 c4 = *reinterpret_cast<const float4*>(ccg + k0 + 8 * j + 4 * g);
            const float cce[4] = {c4.x, c4.y, c4.z, c4.w};
            #pragma unroll
            for (int e = 0; e < 4; ++e) {
                const int r = 4 * j + e;
                float dot  = __fadd_rn(__fadd_rn(aL[r], aM[r]), aH[r]);
                float dist = __fsub_rn(__fadd_rn(zz, cce[e]),
                                       __fmul_rn(2.0f, dot));
                const int k = k0 + 8 * j + 4 * g + e;    // ascending within lane
                if (dist < bd) { bd = dist; bk = k; }
            }
        }
    }

    // ---- argmin merge: cross-half shuffle, then LDS u64 atomicMin ----
    {
        unsigned long long pk =
            (((unsigned long long)__float_as_uint(bd)) << 32) | (unsigned)bk;
        unsigned long long other =
            (unsigned long long)__shfl_xor((long long)pk, 32, 64);
        if (other < pk) pk = other;
        if (g == 0) atomicMin(&best[li], pk);            // tie -> lower k
    }
    __syncthreads();

    // ---- epilogue: thread t < 32 <-> block-local vector t ----
    if (t < 32) {
        const int nn = (blk << 5) + t;
        const size_t zb2 = ((size_t)(nn >> 10) << 16) + (size_t)(nn & 1023);
        const int bkv = (int)(best[t] & 0xFFFFFFFFull);
        out[OFF_IDX + nn] = (float)bkv;
        atomicAdd(&hist[bkv], 1u);
        const float4* qrow = reinterpret_cast<const float4*>(cb + ((size_t)bkv << 6));
        float sq = 0.0f;
        #pragma unroll
        for (int j = 0; j < 16; ++j) {
            float4 q4 = qrow[j];
            const float qa[4] = {q4.x, q4.y, q4.z, q4.w};
            #pragma unroll
            for (int e = 0; e < 4; ++e) {
                const int d = 4 * j + e;
                out[zb2 + ((size_t)d << 10)] = qa[e];        // z_q_st == z_q
                float zx = ze[zb2 + ((size_t)d << 10)];
                float diff = __fsub_rn(qa[e], zx);
                sq = __fadd_rn(sq, __fmul_rn(diff, diff));
            }
        }
        #pragma unroll
        for (int off = 16; off > 0; off >>= 1) sq += __shfl_down(sq, off, 32);
        if (t == 0) partial[blk] = sq;
    }
}

// ---------------- fallback fp32 kernel (round-3, known-good) ----------------
__global__ __launch_bounds__(512, 4) void vq_main_fb(const float* __restrict__ ze,
                                                     const float* __restrict__ cb,
                                                     const float* __restrict__ cc,
                                                     unsigned* __restrict__ hist,
                                                     float* __restrict__ partial,
                                                     float* __restrict__ out) {
    const int lane = threadIdx.x & 63;
    const int w = __builtin_amdgcn_readfirstlane(threadIdx.x >> 6);
    const int n  = blockIdx.x * 64 + lane;
    const int b  = n >> 10;
    const int hw = n & 1023;
    const size_t zbase = ((size_t)b << 16) + (size_t)hw;
    float z[64];
    #pragma unroll
    for (int d = 0; d < 64; ++d) z[d] = ze[zbase + ((size_t)d << 10)];
    float zz = 0.0f;
    #pragma unroll
    for (int d = 0; d < 64; ++d) zz = __fadd_rn(zz, __fmul_rn(z[d], z[d]));
    float best = INFINITY; int bestk = 0;
    const int k0 = w << 7;
    for (int kk = 0; kk < 128; ++kk) {
        const int k = k0 + kk;
        const float4* crow = reinterpret_cast<const float4*>(cb + (k << 6));
        float p[4] = {0.0f, 0.0f, 0.0f, 0.0f};
        #pragma unroll
        for (int j = 0; j < 16; ++j) {
            float4 c4 = crow[j];
            p[j & 3] = fmaf(z[4*j + 0], c4.x, p[j & 3]);
            p[j & 3] = fmaf(z[4*j + 1], c4.y, p[j & 3]);
            p[j & 3] = fmaf(z[4*j + 2], c4.z, p[j & 3]);
            p[j & 3] = fmaf(z[4*j + 3], c4.w, p[j & 3]);
        }
        float dot  = __fadd_rn(__fadd_rn(p[0], p[1]), __fadd_rn(p[2], p[3]));
        float dist = __fsub_rn(__fadd_rn(zz, cc[k]), __fmul_rn(2.0f, dot));
        if (dist < best) { best = dist; bestk = k; }
    }
    __shared__ float s_best[7][64];
    __shared__ int   s_bk[7][64];
    if (w > 0) { s_best[w - 1][lane] = best; s_bk[w - 1][lane] = bestk; }
    __syncthreads();
    if (w == 0) {
        #pragma unroll
        for (int i = 0; i < 7; ++i) {
            float b2 = s_best[i][lane]; int k2 = s_bk[i][lane];
            if (b2 < best) { best = b2; bestk = k2; }
        }
        const float4* qrow = reinterpret_cast<const float4*>(cb + (bestk << 6));
        float sq = 0.0f;
        #pragma unroll
        for (int j = 0; j < 16; ++j) {
            float4 q4 = qrow[j];
            const float q[4] = {q4.x, q4.y, q4.z, q4.w};
            #pragma unroll
            for (int e = 0; e < 4; ++e) {
                int d = 4*j + e;
                out[zbase + ((size_t)d << 10)] = q[e];
                float diff = __fsub_rn(q[e], z[d]);
                sq = __fadd_rn(sq, __fmul_rn(diff, diff));
            }
        }
        out[OFF_IDX + n] = (float)bestk;
        atomicAdd(&hist[bestk], 1u);
        #pragma unroll
        for (int off = 32; off > 0; off >>= 1) sq += __shfl_down(sq, off, 64);
        if (lane == 0) partial[blockIdx.x] = sq;
    }
}

// ---------------- finalize ----------------
__global__ __launch_bounds__(256) void vq_fin(const float* __restrict__ partial,
                                              const unsigned* __restrict__ hist,
                                              float* __restrict__ out, int nb) {
    const int t = threadIdx.x;
    const int wid = t >> 6, lane = t & 63;
    __shared__ float s_loss[4], s_ent[4], s_nz[4];
    float v = 0.0f, ent = 0.0f, nz = 0.0f;
    for (int i = t; i < nb; i += 256) v += partial[i];
    #pragma unroll
    for (int i = 0; i < 4; ++i) {
        unsigned c = hist[t + 256 * i];
        float p = (float)c * (1.0f / 65536.0f);
        ent += p * logf(p + 1e-10f);
        if (c > 0u) nz += 1.0f;
    }
    #pragma unroll
    for (int off = 32; off > 0; off >>= 1) {
        v   += __shfl_down(v,   off, 64);
        ent += __shfl_down(ent, off, 64);
        nz  += __shfl_down(nz,  off, 64);
    }
    if (lane == 0) { s_loss[wid] = v; s_ent[wid] = ent; s_nz[wid] = nz; }
    __syncthreads();
    if (t == 0) {
        float S  = (s_loss[0] + s_loss[1]) + (s_loss[2] + s_loss[3]);
        float vq = S * (1.0f / 4194304.0f);
        out[OFF_VQLOSS] = vq;
        out[OFF_COMMIT] = 0.25f * vq;
        float E  = (s_ent[0] + s_ent[1]) + (s_ent[2] + s_ent[3]);
        float NZ = (s_nz[0] + s_nz[1]) + (s_nz[2] + s_nz[3]);
        out[OFF_USAGE] = NZ * (1.0f / 1024.0f);
        out[OFF_PERP]  = expf(-E);
    }
}

extern "C" void kernel_launch(void* const* d_in, const int* in_sizes, int n_in,
                              void* d_out, int out_size, void* d_ws, size_t ws_size,
                              hipStream_t stream) {
    const float* ze = (const float*)d_in[0];
    const float* cb = (const float*)d_in[1];
    float*    out  = (float*)d_out;
    float*    ws_f = (float*)d_ws;
    unsigned* ws_u = (unsigned*)d_ws;
    char*     cafB = (char*)d_ws + CAF_BYTE_OFF;

    const int use_mfma = (ws_size >= (size_t)WS_REQUIRED);

    vq_init<<<dim3(4), dim3(256), 0, stream>>>(cb, ws_f, ws_u, cafB, use_mfma);
    if (use_mfma) {
        vq_main<<<dim3(2048), dim3(256), 0, stream>>>(ze, cb, ws_f, cafB,
                                                      ws_u + 1024, ws_f + 2048, out);
        vq_fin<<<dim3(1), dim3(256), 0, stream>>>(ws_f + 2048, ws_u + 1024, out, 2048);
    } else {
        vq_main_fb<<<dim3(1024), dim3(512), 0, stream>>>(ze, cb, ws_f, ws_u + 1024,
                                                         ws_f + 2048, out);
        vq_fin<<<dim3(1), dim3(256), 0, stream>>>(ws_f + 2048, ws_u + 1024, out, 1024);
    }
}

// Round 9
// 174.026 us; speedup vs baseline: 5.0897x; 5.0897x over previous
//
#include <hip/hip_runtime.h>
#include <math.h>

// VQ-VAE quantizer, MI355X. N=65536 vectors (B64*H32*W32), D=64, K=1024.
// Round-9: barrier-free MFMA grind, spill-fixed.
//  R8 post-mortem: compiler clamped VGPR to 128 (needed ~170) despite
//  launch_bounds(256,2) -> scratch spill -> 2.9 GB HBM traffic, L2 thrash,
//  MfmaUtil 2%. Fixes:
//   (a) amdgpu_waves_per_eu(2,2): min=max=2 -> reg cap 256, heuristic has no
//       occupancy incentive to under-allocate. Live regs ~225.
//   (b) wave covers 64 vectors (2 n-tiles) per A-frag load: L2 A-traffic
//       786 -> 393 MB; accumulators 3 -> 2 chains (aH=c1z1, aL=5 correction
//       terms; reorder perturbs dot ~2^-33 rel, 5 orders below the 1.5e-8
//       that passed R5-R8).
//  Structure: block = 4 independent waves, all sharing the block's 64 vectors;
//  wave w scans K-quarter w (8 k-tiles x 32 codes); NO in-loop barriers
//  (R5-R7: lockstep convoy pinned MfmaUtil at 31% at any occupancy).
//  A-frags pre-swizzled in ws by vq_init (R8 layout, coalesced 1KB loads).
//  Merge via LDS u64 atomicMin (order-independent, ties -> lower k; R4-proven).
//  dist = fl(fl(zz+cc) - fl(2*dot)), ascending zz/cc chains: bit-identical
//  to rounds 1-8.
//
// ws layout:
//   float ws_f[0..1024)    cc[k] = |codebook_k|^2
//   uint  ws_u[1024..2048) histogram
//   float ws_f[2048..3072) per-block partial sums (1024 blocks)
//   byte 16384..409600     codebook bf16x3 A-fragments (R8 layout):
//     addr = kt*12288 + s*4096 + kc*1024 + li*32 + g*16   (kt=k>>5, li=k&31)
// If ws_size < 409600 -> fallback fp32 kernel (round-3, known-good).

#define OFF_VQLOSS  4194304
#define OFF_COMMIT  4194305
#define OFF_IDX     4194306
#define OFF_USAGE   4259842
#define OFF_PERP    4259843

#define CAF_BYTE_OFF 16384
#define KT_BYTES     12288
#define WS_REQUIRED  (CAF_BYTE_OFF + 32 * KT_BYTES)   // 409,600

typedef __attribute__((ext_vector_type(8)))  short short8;   // 8 bf16 = 4 VGPR
typedef __attribute__((ext_vector_type(16))) float f32x16;

__device__ inline unsigned short f2bf(float x) {             // round-to-nearest-even
    unsigned u = __float_as_uint(x);
    return (unsigned short)((u + 0x7FFFu + ((u >> 16) & 1u)) >> 16);
}
__device__ inline float bf2f(unsigned short h) {
    return __uint_as_float(((unsigned)h) << 16);
}

// ---------------- init: cc, hist zero, codebook bf16x3 A-fragments ----------------
__global__ __launch_bounds__(256) void vq_init(const float* __restrict__ cb,
                                               float* __restrict__ ws_f,
                                               unsigned* __restrict__ ws_u,
                                               char* __restrict__ cafB,
                                               int do_caf) {
    int k = blockIdx.x * 256 + threadIdx.x;    // grid 4x256 -> k in [0,1024)
    ws_u[1024 + k] = 0u;
    const float* row = cb + k * 64;
    float acc = 0.0f;
    #pragma unroll
    for (int d = 0; d < 64; ++d) {
        float v = row[d];
        acc = __fadd_rn(acc, __fmul_rn(v, v));  // ascending chain = rounds 1-8
    }
    ws_f[k] = acc;

    if (!do_caf) return;
    const int kt = k >> 5, li = k & 31;
    #pragma unroll
    for (int q = 0; q < 8; ++q) {              // q = d-octet; kc=q>>1, g=q&1
        unsigned long long u[3][2] = {{0,0},{0,0},{0,0}};
        #pragma unroll
        for (int e = 0; e < 8; ++e) {
            float x = row[q * 8 + e];
            unsigned short h1 = f2bf(x);  float r1 = __fsub_rn(x,  bf2f(h1));
            unsigned short h2 = f2bf(r1); float r2 = __fsub_rn(r1, bf2f(h2));
            unsigned short h3 = f2bf(r2);
            const int hw = e >> 2, sh = 16 * (e & 3);
            u[0][hw] |= ((unsigned long long)h1) << sh;
            u[1][hw] |= ((unsigned long long)h2) << sh;
            u[2][hw] |= ((unsigned long long)h3) << sh;
        }
        const int kc = q >> 1, g = q & 1;
        char* dst = cafB + (size_t)kt * KT_BYTES + kc * 1024 + li * 32 + g * 16;
        #pragma unroll
        for (int s = 0; s < 3; ++s) {
            *reinterpret_cast<unsigned long long*>(dst + s * 4096 + 0) = u[s][0];
            *reinterpret_cast<unsigned long long*>(dst + s * 4096 + 8) = u[s][1];
        }
    }
}

// ---------------- main: barrier-free MFMA grind + argmin + epilogue ----------------
// 1024 blocks x 64 vectors; 4 waves/block; wave w scans codes
// [w*256, w*256+256) over the block's 64 vectors (2 n-tiles of 32).
__global__ __launch_bounds__(256)
__attribute__((amdgpu_waves_per_eu(2, 2)))
void vq_main(const float* __restrict__ ze,
             const float* __restrict__ cb,
             const float* __restrict__ ccg,
             const char* __restrict__ cafB,
             unsigned* __restrict__ hist,
             float* __restrict__ partial,
             float* __restrict__ out) {
    const int t    = threadIdx.x;
    const int w    = t >> 6;            // wave = K-quarter 0..3
    const int lane = t & 63;
    const int li   = lane & 31;         // MFMA row/col index
    const int g    = lane >> 5;         // half-wave group (d-octet select)
    const int blk  = blockIdx.x;        // 1024 blocks x 64 vectors

    __shared__ unsigned long long best[64];
    if (t < 64) best[t] = ~0ull;

    // ---- load z, compute zz (ascending chain, bit-identical to R1-8),
    //      build resident bf16x3 B-fragments for the wave's 2 n-tiles ----
    float zz[2], bd[2];
    int   bk[2];
    short8 zf[2][3][4];                 // [nt][split][kc]
    #pragma unroll
    for (int nt = 0; nt < 2; ++nt) {
        const int n = (blk << 6) + (nt << 5) + li;
        const size_t zb = ((size_t)(n >> 10) << 16) + (size_t)(n & 1023);
        float s = 0.0f;
        #pragma unroll
        for (int d = 0; d < 64; ++d) {
            float x = ze[zb + ((size_t)d << 10)];
            s = __fadd_rn(s, __fmul_rn(x, x));
        }
        zz[nt] = s; bd[nt] = INFINITY; bk[nt] = 0;
        #pragma unroll
        for (int kc = 0; kc < 4; ++kc) {
            unsigned long long u[3][2] = {{0,0},{0,0},{0,0}};
            #pragma unroll
            for (int e = 0; e < 8; ++e) {
                int d = kc * 16 + (g << 3) + e;
                float x = ze[zb + ((size_t)d << 10)];    // L1-hot re-read
                unsigned short h1 = f2bf(x);  float r1 = __fsub_rn(x,  bf2f(h1));
                unsigned short h2 = f2bf(r1); float r2 = __fsub_rn(r1, bf2f(h2));
                unsigned short h3 = f2bf(r2);
                const int hw = e >> 2, sh = 16 * (e & 3);
                u[0][hw] |= ((unsigned long long)h1) << sh;
                u[1][hw] |= ((unsigned long long)h2) << sh;
                u[2][hw] |= ((unsigned long long)h3) << sh;
            }
            #pragma unroll
            for (int s2 = 0; s2 < 3; ++s2) {
                union { unsigned long long uu[2]; short8 v; } cvt;
                cvt.uu[0] = u[s2][0]; cvt.uu[1] = u[s2][1];
                zf[nt][s2][kc] = cvt.v;
            }
        }
    }

    __syncthreads();                    // best[] init visible; only pre-merge barrier

    // ---- 8 k-tiles of 32 codes, fully independent per wave, no barriers ----
    #pragma unroll
    for (int kt2 = 0; kt2 < 8; ++kt2) {
        const int kt = (w << 3) + kt2;
        const int k0 = kt << 5;

        // 12 coalesced 1KB A-frag loads from L2 (pre-swizzled layout)
        const char* abase = cafB + (size_t)kt * KT_BYTES + li * 32 + g * 16;
        short8 a[4][3];
        #pragma unroll
        for (int kc = 0; kc < 4; ++kc)
            #pragma unroll
            for (int s2 = 0; s2 < 3; ++s2)
                a[kc][s2] = *reinterpret_cast<const short8*>(abase + s2 * 4096 + kc * 1024);

        f32x16 aH[2], aL[2];
        #pragma unroll
        for (int nt = 0; nt < 2; ++nt)
            #pragma unroll
            for (int r = 0; r < 16; ++r) { aH[nt][r] = 0.0f; aL[nt][r] = 0.0f; }

        #pragma unroll
        for (int kc = 0; kc < 4; ++kc) {
            #pragma unroll
            for (int nt = 0; nt < 2; ++nt) {
                // 6 terms, 2 chains: aL = 5 correction terms (smallest first),
                // aH = c1z1. (drop c3z2, c2z3, c3z3 as in R6-R8)
                aL[nt] = __builtin_amdgcn_mfma_f32_32x32x16_bf16(a[kc][1], zf[nt][1][kc], aL[nt], 0, 0, 0); // c2 z2
                aL[nt] = __builtin_amdgcn_mfma_f32_32x32x16_bf16(a[kc][2], zf[nt][0][kc], aL[nt], 0, 0, 0); // c3 z1
                aL[nt] = __builtin_amdgcn_mfma_f32_32x32x16_bf16(a[kc][0], zf[nt][2][kc], aL[nt], 0, 0, 0); // c1 z3
                aL[nt] = __builtin_amdgcn_mfma_f32_32x32x16_bf16(a[kc][1], zf[nt][0][kc], aL[nt], 0, 0, 0); // c2 z1
                aL[nt] = __builtin_amdgcn_mfma_f32_32x32x16_bf16(a[kc][0], zf[nt][1][kc], aL[nt], 0, 0, 0); // c1 z2
                aH[nt] = __builtin_amdgcn_mfma_f32_32x32x16_bf16(a[kc][0], zf[nt][0][kc], aH[nt], 0, 0, 0); // c1 z1
            }
        }
        // dist + running argmin. C/D: col=lane&31 (vector), row=(r&3)+8*(r>>2)+4g
        #pragma unroll
        for (int j = 0; j < 4; ++j) {
            float4 c4 = *reinterpret_cast<const float4*>(ccg + k0 + 8 * j + 4 * g);
            const float cce[4] = {c4.x, c4.y, c4.z, c4.w};
            #pragma unroll
            for (int e = 0; e < 4; ++e) {
                const int r = 4 * j + e;
                const int k = k0 + 8 * j + 4 * g + e;    // ascending within lane
                #pragma unroll
                for (int nt = 0; nt < 2; ++nt) {
                    float dot  = __fadd_rn(aL[nt][r], aH[nt][r]);
                    float dist = __fsub_rn(__fadd_rn(zz[nt], cce[e]),
                                           __fmul_rn(2.0f, dot));
                    if (dist < bd[nt]) { bd[nt] = dist; bk[nt] = k; }
                }
            }
        }
    }

    // ---- argmin merge: cross-half shuffle, then LDS u64 atomicMin ----
    #pragma unroll
    for (int nt = 0; nt < 2; ++nt) {
        unsigned long long pk =
            (((unsigned long long)__float_as_uint(bd[nt])) << 32) | (unsigned)bk[nt];
        unsigned long long other =
            (unsigned long long)__shfl_xor((long long)pk, 32, 64);
        if (other < pk) pk = other;
        if (g == 0) atomicMin(&best[(nt << 5) + li], pk);    // tie -> lower k
    }
    __syncthreads();

    // ---- epilogue: wave 0, thread t < 64 <-> block-local vector t ----
    if (t < 64) {
        const int nn = (blk << 6) + t;
        const size_t zb2 = ((size_t)(nn >> 10) << 16) + (size_t)(nn & 1023);
        const int bkv = (int)(best[t] & 0xFFFFFFFFull);
        out[OFF_IDX + nn] = (float)bkv;
        atomicAdd(&hist[bkv], 1u);
        const float4* qrow = reinterpret_cast<const float4*>(cb + ((size_t)bkv << 6));
        float sq = 0.0f;
        #pragma unroll
        for (int j = 0; j < 16; ++j) {
            float4 q4 = qrow[j];
            const float qa[4] = {q4.x, q4.y, q4.z, q4.w};
            #pragma unroll
            for (int e = 0; e < 4; ++e) {
                const int d = 4 * j + e;
                out[zb2 + ((size_t)d << 10)] = qa[e];        // z_q_st == z_q
                float zx = ze[zb2 + ((size_t)d << 10)];
                float diff = __fsub_rn(qa[e], zx);
                sq = __fadd_rn(sq, __fmul_rn(diff, diff));
            }
        }
        #pragma unroll
        for (int off = 32; off > 0; off >>= 1) sq += __shfl_down(sq, off, 64);
        if (t == 0) partial[blk] = sq;
    }
}

// ---------------- fallback fp32 kernel (round-3, known-good) ----------------
__global__ __launch_bounds__(512, 4) void vq_main_fb(const float* __restrict__ ze,
                                                     const float* __restrict__ cb,
                                                     const float* __restrict__ cc,
                                                     unsigned* __restrict__ hist,
                                                     float* __restrict__ partial,
                                                     float* __restrict__ out) {
    const int lane = threadIdx.x & 63;
    const int w = __builtin_amdgcn_readfirstlane(threadIdx.x >> 6);
    const int n  = blockIdx.x * 64 + lane;
    const int b  = n >> 10;
    const int hw = n & 1023;
    const size_t zbase = ((size_t)b << 16) + (size_t)hw;
    float z[64];
    #pragma unroll
    for (int d = 0; d < 64; ++d) z[d] = ze[zbase + ((size_t)d << 10)];
    float zz = 0.0f;
    #pragma unroll
    for (int d = 0; d < 64; ++d) zz = __fadd_rn(zz, __fmul_rn(z[d], z[d]));
    float best = INFINITY; int bestk = 0;
    const int k0 = w << 7;
    for (int kk = 0; kk < 128; ++kk) {
        const int k = k0 + kk;
        const float4* crow = reinterpret_cast<const float4*>(cb + (k << 6));
        float p[4] = {0.0f, 0.0f, 0.0f, 0.0f};
        #pragma unroll
        for (int j = 0; j < 16; ++j) {
            float4 c4 = crow[j];
            p[j & 3] = fmaf(z[4*j + 0], c4.x, p[j & 3]);
            p[j & 3] = fmaf(z[4*j + 1], c4.y, p[j & 3]);
            p[j & 3] = fmaf(z[4*j + 2], c4.z, p[j & 3]);
            p[j & 3] = fmaf(z[4*j + 3], c4.w, p[j & 3]);
        }
        float dot  = __fadd_rn(__fadd_rn(p[0], p[1]), __fadd_rn(p[2], p[3]));
        float dist = __fsub_rn(__fadd_rn(zz, cc[k]), __fmul_rn(2.0f, dot));
        if (dist < best) { best = dist; bestk = k; }
    }
    __shared__ float s_best[7][64];
    __shared__ int   s_bk[7][64];
    if (w > 0) { s_best[w - 1][lane] = best; s_bk[w - 1][lane] = bestk; }
    __syncthreads();
    if (w == 0) {
        #pragma unroll
        for (int i = 0; i < 7; ++i) {
            float b2 = s_best[i][lane]; int k2 = s_bk[i][lane];
            if (b2 < best) { best = b2; bestk = k2; }
        }
        const float4* qrow = reinterpret_cast<const float4*>(cb + (bestk << 6));
        float sq = 0.0f;
        #pragma unroll
        for (int j = 0; j < 16; ++j) {
            float4 q4 = qrow[j];
            const float q[4] = {q4.x, q4.y, q4.z, q4.w};
            #pragma unroll
            for (int e = 0; e < 4; ++e) {
                int d = 4*j + e;
                out[zbase + ((size_t)d << 10)] = q[e];
                float diff = __fsub_rn(q[e], z[d]);
                sq = __fadd_rn(sq, __fmul_rn(diff, diff));
            }
        }
        out[OFF_IDX + n] = (float)bestk;
        atomicAdd(&hist[bestk], 1u);
        #pragma unroll
        for (int off = 32; off > 0; off >>= 1) sq += __shfl_down(sq, off, 64);
        if (lane == 0) partial[blockIdx.x] = sq;
    }
}

// ---------------- finalize ----------------
__global__ __launch_bounds__(256) void vq_fin(const float* __restrict__ partial,
                                              const unsigned* __restrict__ hist,
                                              float* __restrict__ out, int nb) {
    const int t = threadIdx.x;
    const int wid = t >> 6, lane = t & 63;
    __shared__ float s_loss[4], s_ent[4], s_nz[4];
    float v = 0.0f, ent = 0.0f, nz = 0.0f;
    for (int i = t; i < nb; i += 256) v += partial[i];
    #pragma unroll
    for (int i = 0; i < 4; ++i) {
        unsigned c = hist[t + 256 * i];
        float p = (float)c * (1.0f / 65536.0f);
        ent += p * logf(p + 1e-10f);
        if (c > 0u) nz += 1.0f;
    }
    #pragma unroll
    for (int off = 32; off > 0; off >>= 1) {
        v   += __shfl_down(v,   off, 64);
        ent += __shfl_down(ent, off, 64);
        nz  += __shfl_down(nz,  off, 64);
    }
    if (lane == 0) { s_loss[wid] = v; s_ent[wid] = ent; s_nz[wid] = nz; }
    __syncthreads();
    if (t == 0) {
        float S  = (s_loss[0] + s_loss[1]) + (s_loss[2] + s_loss[3]);
        float vq = S * (1.0f / 4194304.0f);
        out[OFF_VQLOSS] = vq;
        out[OFF_COMMIT] = 0.25f * vq;
        float E  = (s_ent[0] + s_ent[1]) + (s_ent[2] + s_ent[3]);
        float NZ = (s_nz[0] + s_nz[1]) + (s_nz[2] + s_nz[3]);
        out[OFF_USAGE] = NZ * (1.0f / 1024.0f);
        out[OFF_PERP]  = expf(-E);
    }
}

extern "C" void kernel_launch(void* const* d_in, const int* in_sizes, int n_in,
                              void* d_out, int out_size, void* d_ws, size_t ws_size,
                              hipStream_t stream) {
    const float* ze = (const float*)d_in[0];
    const float* cb = (const float*)d_in[1];
    float*    out  = (float*)d_out;
    float*    ws_f = (float*)d_ws;
    unsigned* ws_u = (unsigned*)d_ws;
    char*     cafB = (char*)d_ws + CAF_BYTE_OFF;

    const int use_mfma = (ws_size >= (size_t)WS_REQUIRED);

    vq_init<<<dim3(4), dim3(256), 0, stream>>>(cb, ws_f, ws_u, cafB, use_mfma);
    if (use_mfma) {
        vq_main<<<dim3(1024), dim3(256), 0, stream>>>(ze, cb, ws_f, cafB,
                                                      ws_u + 1024, ws_f + 2048, out);
        vq_fin<<<dim3(1), dim3(256), 0, stream>>>(ws_f + 2048, ws_u + 1024, out, 1024);
    } else {
        vq_main_fb<<<dim3(1024), dim3(512), 0, stream>>>(ze, cb, ws_f, ws_u + 1024,
                                                         ws_f + 2048, out);
        vq_fin<<<dim3(1), dim3(256), 0, stream>>>(ws_f + 2048, ws_u + 1024, out, 1024);
    }
}

// Round 10
// 75.124 us; speedup vs baseline: 11.7903x; 2.3165x over previous
//
#include <hip/hip_runtime.h>
#include <math.h>

// VQ-VAE quantizer, MI355X. N=65536 vectors (B64*H32*W32), D=64, K=1024.
// Round-10: R7 structure (proven: VGPR 64, no spill, absmax 1.5e-5) with the
// per-chunk vmcnt(0) DRAIN removed -> T4 counted-vmcnt pipeline.
//  R8/R9 post-mortem: barrier-free needs ~170-225 VGPR; allocator caps at 128
//  -> scratch spill (95MB-1.9GB extra HBM). Abandoned.
//  True MFMA floor: 1.57M mfma x 8cyc / 1024 SIMD = 5.1us. R7's 70us is
//  structure overhead: per-chunk {compute; s_waitcnt vmcnt(0); barrier}
//  drains ALL in-flight stages every 32 codes (m233 2-phase stall).
//  Fix (T3/T4): per chunk {counted vmcnt (own 3-4 loads) -> barrier ->
//  setprio(1) MFMA setprio(0) -> argmin -> barrier -> issue stage(ci+2)}.
//  Next-chunk loads stay in flight across barriers; vmcnt(0) only at ci=15.
//  All numerics bit-identical to rounds 5-9 (6-term bf16x3, 3 chains,
//  dist = fl(fl(zz+cc) - fl(2*dot)), ascending chains, ties -> lower k).
//
// ws layout:
//   float ws_f[0..1024)    cc[k] = |codebook_k|^2
//   uint  ws_u[1024..2048) histogram
//   float ws_f[2048..2560) per-block partial sums (512 blocks)
//   byte 12288..438272     codebook bf16x3 splits, 32 chunks x 13312B
//                          per chunk: [split s: 544 u64][row cl: 17 u64 (16+pad)]
// If ws_size < 438272 -> fallback fp32 kernel (round-3, known-good).

#define OFF_VQLOSS  4194304
#define OFF_COMMIT  4194305
#define OFF_IDX     4194306
#define OFF_USAGE   4259842
#define OFF_PERP    4259843

#define CBS_BYTE_OFF 12288
#define CHUNK_BYTES  13312          // 3 splits * 32 rows * 17*8B = 13056, pad to 13*1024
#define N_CHUNKS     32
#define WS_REQUIRED  (CBS_BYTE_OFF + N_CHUNKS * CHUNK_BYTES)

typedef __attribute__((ext_vector_type(8)))  short short8;   // 8 bf16 = 4 VGPR
typedef __attribute__((ext_vector_type(16))) float f32x16;

__device__ inline unsigned short f2bf(float x) {             // round-to-nearest-even
    unsigned u = __float_as_uint(x);
    return (unsigned short)((u + 0x7FFFu + ((u >> 16) & 1u)) >> 16);
}
__device__ inline float bf2f(unsigned short h) {
    return __uint_as_float(((unsigned)h) << 16);
}
__device__ inline void gload_lds16(const void* g, void* l) { // async 16B global->LDS
    __builtin_amdgcn_global_load_lds((const __attribute__((address_space(1))) void*)g,
                                     (__attribute__((address_space(3))) void*)l, 16, 0, 0);
}

// ---------------- init: cc, hist zero, codebook bf16x3 splits ----------------
// grid 32 x 256 = 8192 threads: unit = (k, d-octet q). R9's 4-block version was
// ~4us of serial pack work on 4 CUs; this spreads it over 32 CUs.
__global__ __launch_bounds__(256) void vq_init(const float* __restrict__ cb,
                                               float* __restrict__ ws_f,
                                               unsigned* __restrict__ ws_u,
                                               unsigned long long* __restrict__ cbs8,
                                               int do_cbs) {
    const int idx = blockIdx.x * 256 + threadIdx.x;   // 0..8191
    if (idx < 1024) {
        ws_u[1024 + idx] = 0u;                        // zero histogram every launch
        const float* row = cb + idx * 64;
        float acc = 0.0f;
        #pragma unroll
        for (int d = 0; d < 64; ++d) {
            float v = row[d];
            acc = __fadd_rn(acc, __fmul_rn(v, v));    // ascending chain = rounds 1-9
        }
        ws_f[idx] = acc;
    }
    if (!do_cbs) return;
    const int k = idx >> 3, q = idx & 7;              // q = d-octet
    const float* row = cb + k * 64;
    unsigned long long u[3][2] = {{0,0},{0,0},{0,0}};
    #pragma unroll
    for (int e = 0; e < 8; ++e) {
        float x = row[q * 8 + e];
        unsigned short h1 = f2bf(x);  float r1 = __fsub_rn(x,  bf2f(h1));
        unsigned short h2 = f2bf(r1); float r2 = __fsub_rn(r1, bf2f(h2));
        unsigned short h3 = f2bf(r2);
        const int hw = e >> 2, sh = 16 * (e & 3);
        u[0][hw] |= ((unsigned long long)h1) << sh;
        u[1][hw] |= ((unsigned long long)h2) << sh;
        u[2][hw] |= ((unsigned long long)h3) << sh;
    }
    // chunk ch = k>>5 (32 codes/chunk), row cl = k&31; row = 17 u64 (16 + pad)
    const int ch = k >> 5, cl = k & 31;
    unsigned long long* base = cbs8 + (size_t)ch * (CHUNK_BYTES / 8) + (size_t)cl * 17;
    #pragma unroll
    for (int s = 0; s < 3; ++s) {
        base[(size_t)s * 544 + q * 2 + 0] = u[s][0];  // 544 = 32*17 u64/split
        base[(size_t)s * 544 + q * 2 + 1] = u[s][1];
    }
}

// ---------------- main: MFMA distance GEMM + argmin + epilogue ----------------
// 512 blocks x 128 vectors; 8 waves: group grp=w>>2 scans K-half grp,
// wave-in-group wg=w&3 owns vectors wg*32..wg*32+31.
__global__ __launch_bounds__(512, 4) void vq_main(const float* __restrict__ ze,
                                                  const float* __restrict__ cb,
                                                  const float* __restrict__ ccg,
                                                  const unsigned long long* __restrict__ cbs8,
                                                  unsigned* __restrict__ hist,
                                                  float* __restrict__ partial,
                                                  float* __restrict__ out) {
    const int t    = threadIdx.x;
    const int w    = t >> 6;            // wave 0..7
    const int lane = t & 63;
    const int li   = lane & 31;         // MFMA row/col index
    const int g    = lane >> 5;         // half-wave group (k-octet select)
    const int grp  = __builtin_amdgcn_readfirstlane(w >> 2);  // K-half 0/1
    const int wg   = __builtin_amdgcn_readfirstlane(w & 3);   // wave within group
    const int blk  = blockIdx.x;        // 512 blocks x 128 vectors

    __shared__ char  chunkbuf[2][2][CHUNK_BYTES];   // [grp][dbuf]
    __shared__ float cc_lds[1024];
    __shared__ unsigned long long best[128];
    __shared__ float sred[2];

    // ---- prologue: issue stages of chunks 0 and 1 (async, stay in flight) ----
    {
        const char* src0 = (const char*)cbs8 + (size_t)(grp * 16) * CHUNK_BYTES;
        char* dst0 = &chunkbuf[grp][0][0];
        for (int r = wg; r < 13; r += 4)
            gload_lds16(src0 + r * 1024 + lane * 16, dst0 + r * 1024);
        const char* src1 = src0 + CHUNK_BYTES;
        char* dst1 = &chunkbuf[grp][1][0];
        for (int r = wg; r < 13; r += 4)
            gload_lds16(src1 + r * 1024 + lane * 16, dst1 + r * 1024);
    }
    if (t < 256) {                       // cc -> LDS (overlaps staging)
        float4 c4 = *reinterpret_cast<const float4*>(ccg + t * 4);
        *reinterpret_cast<float4*>(&cc_lds[t * 4]) = c4;
    }
    if (t < 128) best[t] = ~0ull;

    // ---- load z, compute zz (ascending chain, bit-identical to R1-9),
    //      build resident bf16x3 B-fragments (this wave's 32 vectors) ----
    const int vloc = (wg << 5) + li;
    const int n    = (blk << 7) + vloc;
    const size_t zb = ((size_t)(n >> 10) << 16) + (size_t)(n & 1023);
    float zz, bd;
    int   bk;
    short8 zf[3][4];                    // [split][kc]
    {
        float s = 0.0f;
        #pragma unroll
        for (int d = 0; d < 64; ++d) {
            float x = ze[zb + ((size_t)d << 10)];
            s = __fadd_rn(s, __fmul_rn(x, x));
        }
        zz = s; bd = INFINITY; bk = 0;
        #pragma unroll
        for (int kc = 0; kc < 4; ++kc) {
            unsigned long long u[3][2] = {{0,0},{0,0},{0,0}};
            #pragma unroll
            for (int e = 0; e < 8; ++e) {
                int d = kc * 16 + (g << 3) + e;
                float x = ze[zb + ((size_t)d << 10)];    // L1-hot re-read
                unsigned short h1 = f2bf(x);  float r1 = __fsub_rn(x,  bf2f(h1));
                unsigned short h2 = f2bf(r1); float r2 = __fsub_rn(r1, bf2f(h2));
                unsigned short h3 = f2bf(r2);
                const int hw = e >> 2, sh = 16 * (e & 3);
                u[0][hw] |= ((unsigned long long)h1) << sh;
                u[1][hw] |= ((unsigned long long)h2) << sh;
                u[2][hw] |= ((unsigned long long)h3) << sh;
            }
            #pragma unroll
            for (int s2 = 0; s2 < 3; ++s2) {
                union { unsigned long long uu[2]; short8 v; } cvt;
                cvt.uu[0] = u[s2][0]; cvt.uu[1] = u[s2][1];
                zf[s2][kc] = cvt.v;
            }
        }
    }

    // ---- 16 chunks of 32 codes per group, counted-vmcnt double-buffer ----
    // In flight at chunk ci entry: stage(ci) + stage(ci+1). Counted wait
    // retires stage(ci) only; stage(ci+1) stays in flight across the barrier
    // (T4 - never vmcnt(0) in the loop).
    for (int ci = 0; ci < 16; ++ci) {
        const int cur = ci & 1;
        if (ci < 15) {
            if (wg == 0) asm volatile("s_waitcnt vmcnt(4)" ::: "memory");
            else         asm volatile("s_waitcnt vmcnt(3)" ::: "memory");
        } else {
            asm volatile("s_waitcnt vmcnt(0)" ::: "memory");
        }
        __syncthreads();                                 // all waves' ci loads visible

        const unsigned long long* b8 =
            (const unsigned long long*)&chunkbuf[grp][cur][0];

        f32x16 aH, aM, aL;
        #pragma unroll
        for (int r = 0; r < 16; ++r) { aH[r] = 0.0f; aM[r] = 0.0f; aL[r] = 0.0f; }

        const int cl = li;                               // code row (A: m = lane&31)
        __builtin_amdgcn_s_setprio(1);
        #pragma unroll
        for (int kc = 0; kc < 4; ++kc) {
            short8 a[3];
            #pragma unroll
            for (int s2 = 0; s2 < 3; ++s2) {             // adjacent u64 pair
                int a8 = s2 * 544 + cl * 17 + (kc * 2 + g) * 2;
                union { unsigned long long uu[2]; short8 v; } cvt;
                cvt.uu[0] = b8[a8]; cvt.uu[1] = b8[a8 + 1];
                a[s2] = cvt.v;
            }
            // 6 terms, 3 independent chains (drop c3z2, c2z3, c3z3)
            aL = __builtin_amdgcn_mfma_f32_32x32x16_bf16(a[1], zf[1][kc], aL, 0, 0, 0); // c2 z2
            aL = __builtin_amdgcn_mfma_f32_32x32x16_bf16(a[2], zf[0][kc], aL, 0, 0, 0); // c3 z1
            aL = __builtin_amdgcn_mfma_f32_32x32x16_bf16(a[0], zf[2][kc], aL, 0, 0, 0); // c1 z3
            aM = __builtin_amdgcn_mfma_f32_32x32x16_bf16(a[1], zf[0][kc], aM, 0, 0, 0); // c2 z1
            aM = __builtin_amdgcn_mfma_f32_32x32x16_bf16(a[0], zf[1][kc], aM, 0, 0, 0); // c1 z2
            aH = __builtin_amdgcn_mfma_f32_32x32x16_bf16(a[0], zf[0][kc], aH, 0, 0, 0); // c1 z1
        }
        __builtin_amdgcn_s_setprio(0);

        // dist + running argmin. C/D: col=lane&31 (vector), row=(r&3)+8*(r>>2)+4g
        const int k0 = (grp << 9) + (ci << 5);
        #pragma unroll
        for (int j = 0; j < 4; ++j) {
            float4 c4 = *reinterpret_cast<const float4*>(&cc_lds[k0 + 8 * j + 4 * g]);
            const float cce[4] = {c4.x, c4.y, c4.z, c4.w};
            #pragma unroll
            for (int e = 0; e < 4; ++e) {
                const int r = 4 * j + e;
                float dot  = __fadd_rn(__fadd_rn(aL[r], aM[r]), aH[r]);
                float dist = __fsub_rn(__fadd_rn(zz, cce[e]),
                                       __fmul_rn(2.0f, dot));
                const int k = k0 + 8 * j + 4 * g + e;    // ascending within lane
                if (dist < bd) { bd = dist; bk = k; }
            }
        }

        __syncthreads();                                 // buf[cur] reads complete
        if (ci + 2 < 16) {                               // refill buf[cur] (async)
            const char* src = (const char*)cbs8
                            + (size_t)(grp * 16 + ci + 2) * CHUNK_BYTES;
            char* dst = &chunkbuf[grp][cur][0];
            for (int r = wg; r < 13; r += 4)
                gload_lds16(src + r * 1024 + lane * 16, dst + r * 1024);
        }
    }

    // ---- argmin merge: cross-half shuffle, then cross-group LDS atomicMin ----
    {
        unsigned long long pk =
            (((unsigned long long)__float_as_uint(bd)) << 32) | (unsigned)bk;
        unsigned long long other =
            (unsigned long long)__shfl_xor((long long)pk, 32, 64);
        if (other < pk) pk = other;
        if (g == 0) atomicMin(&best[vloc], pk);          // tie -> lower k
    }
    __syncthreads();

    // ---- epilogue: thread t < 128 <-> block-local vector t ----
    if (t < 128) {
        const int nn = (blk << 7) + t;
        const size_t zb2 = ((size_t)(nn >> 10) << 16) + (size_t)(nn & 1023);
        const int bkv = (int)(best[t] & 0xFFFFFFFFull);
        out[OFF_IDX + nn] = (float)bkv;
        atomicAdd(&hist[bkv], 1u);
        const float4* qrow = reinterpret_cast<const float4*>(cb + ((size_t)bkv << 6));
        float sq = 0.0f;
        #pragma unroll
        for (int j = 0; j < 16; ++j) {
            float4 q4 = qrow[j];
            const float qa[4] = {q4.x, q4.y, q4.z, q4.w};
            #pragma unroll
            for (int e = 0; e < 4; ++e) {
                const int d = 4 * j + e;
                out[zb2 + ((size_t)d << 10)] = qa[e];        // z_q_st == z_q
                float zx = ze[zb2 + ((size_t)d << 10)];
                float diff = __fsub_rn(qa[e], zx);
                sq = __fadd_rn(sq, __fmul_rn(diff, diff));
            }
        }
        #pragma unroll
        for (int off = 32; off > 0; off >>= 1) sq += __shfl_down(sq, off, 64);
        if (lane == 0) sred[t >> 6] = sq;
    }
    __syncthreads();
    if (t == 0) partial[blk] = sred[0] + sred[1];
}

// ---------------- fallback fp32 kernel (round-3, known-good) ----------------
__global__ __launch_bounds__(512, 4) void vq_main_fb(const float* __restrict__ ze,
                                                     const float* __restrict__ cb,
                                                     const float* __restrict__ cc,
                                                     unsigned* __restrict__ hist,
                                                     float* __restrict__ partial,
                                                     float* __restrict__ out) {
    const int lane = threadIdx.x & 63;
    const int w = __builtin_amdgcn_readfirstlane(threadIdx.x >> 6);
    const int n  = blockIdx.x * 64 + lane;
    const int b  = n >> 10;
    const int hw = n & 1023;
    const size_t zbase = ((size_t)b << 16) + (size_t)hw;
    float z[64];
    #pragma unroll
    for (int d = 0; d < 64; ++d) z[d] = ze[zbase + ((size_t)d << 10)];
    float zz = 0.0f;
    #pragma unroll
    for (int d = 0; d < 64; ++d) zz = __fadd_rn(zz, __fmul_rn(z[d], z[d]));
    float best = INFINITY; int bestk = 0;
    const int k0 = w << 7;
    for (int kk = 0; kk < 128; ++kk) {
        const int k = k0 + kk;
        const float4* crow = reinterpret_cast<const float4*>(cb + (k << 6));
        float p[4] = {0.0f, 0.0f, 0.0f, 0.0f};
        #pragma unroll
        for (int j = 0; j < 16; ++j) {
            float4 c4 = crow[j];
            p[j & 3] = fmaf(z[4*j + 0], c4.x, p[j & 3]);
            p[j & 3] = fmaf(z[4*j + 1], c4.y, p[j & 3]);
            p[j & 3] = fmaf(z[4*j + 2], c4.z, p[j & 3]);
            p[j & 3] = fmaf(z[4*j + 3], c4.w, p[j & 3]);
        }
        float dot  = __fadd_rn(__fadd_rn(p[0], p[1]), __fadd_rn(p[2], p[3]));
        float dist = __fsub_rn(__fadd_rn(zz, cc[k]), __fmul_rn(2.0f, dot));
        if (dist < best) { best = dist; bestk = k; }
    }
    __shared__ float s_best[7][64];
    __shared__ int   s_bk[7][64];
    if (w > 0) { s_best[w - 1][lane] = best; s_bk[w - 1][lane] = bestk; }
    __syncthreads();
    if (w == 0) {
        #pragma unroll
        for (int i = 0; i < 7; ++i) {
            float b2 = s_best[i][lane]; int k2 = s_bk[i][lane];
            if (b2 < best) { best = b2; bestk = k2; }
        }
        const float4* qrow = reinterpret_cast<const float4*>(cb + (bestk << 6));
        float sq = 0.0f;
        #pragma unroll
        for (int j = 0; j < 16; ++j) {
            float4 q4 = qrow[j];
            const float q[4] = {q4.x, q4.y, q4.z, q4.w};
            #pragma unroll
            for (int e = 0; e < 4; ++e) {
                int d = 4*j + e;
                out[zbase + ((size_t)d << 10)] = q[e];
                float diff = __fsub_rn(q[e], z[d]);
                sq = __fadd_rn(sq, __fmul_rn(diff, diff));
            }
        }
        out[OFF_IDX + n] = (float)bestk;
        atomicAdd(&hist[bestk], 1u);
        #pragma unroll
        for (int off = 32; off > 0; off >>= 1) sq += __shfl_down(sq, off, 64);
        if (lane == 0) partial[blockIdx.x] = sq;
    }
}

// ---------------- finalize ----------------
__global__ __launch_bounds__(256) void vq_fin(const float* __restrict__ partial,
                                              const unsigned* __restrict__ hist,
                                              float* __restrict__ out, int nb) {
    const int t = threadIdx.x;
    const int wid = t >> 6, lane = t & 63;
    __shared__ float s_loss[4], s_ent[4], s_nz[4];
    float v = 0.0f, ent = 0.0f, nz = 0.0f;
    for (int i = t; i < nb; i += 256) v += partial[i];
    #pragma unroll
    for (int i = 0; i < 4; ++i) {
        unsigned c = hist[t + 256 * i];
        float p = (float)c * (1.0f / 65536.0f);
        ent += p * logf(p + 1e-10f);
        if (c > 0u) nz += 1.0f;
    }
    #pragma unroll
    for (int off = 32; off > 0; off >>= 1) {
        v   += __shfl_down(v,   off, 64);
        ent += __shfl_down(ent, off, 64);
        nz  += __shfl_down(nz,  off, 64);
    }
    if (lane == 0) { s_loss[wid] = v; s_ent[wid] = ent; s_nz[wid] = nz; }
    __syncthreads();
    if (t == 0) {
        float S  = (s_loss[0] + s_loss[1]) + (s_loss[2] + s_loss[3]);
        float vq = S * (1.0f / 4194304.0f);
        out[OFF_VQLOSS] = vq;
        out[OFF_COMMIT] = 0.25f * vq;
        float E  = (s_ent[0] + s_ent[1]) + (s_ent[2] + s_ent[3]);
        float NZ = (s_nz[0] + s_nz[1]) + (s_nz[2] + s_nz[3]);
        out[OFF_USAGE] = NZ * (1.0f / 1024.0f);
        out[OFF_PERP]  = expf(-E);
    }
}

extern "C" void kernel_launch(void* const* d_in, const int* in_sizes, int n_in,
                              void* d_out, int out_size, void* d_ws, size_t ws_size,
                              hipStream_t stream) {
    const float* ze = (const float*)d_in[0];
    const float* cb = (const float*)d_in[1];
    float*    out  = (float*)d_out;
    float*    ws_f = (float*)d_ws;
    unsigned* ws_u = (unsigned*)d_ws;
    unsigned long long* cbs8 =
        (unsigned long long*)((char*)d_ws + CBS_BYTE_OFF);

    const int use_mfma = (ws_size >= (size_t)WS_REQUIRED);

    vq_init<<<dim3(use_mfma ? 32 : 4), dim3(256), 0, stream>>>(cb, ws_f, ws_u,
                                                               cbs8, use_mfma);
    if (use_mfma) {
        vq_main<<<dim3(512), dim3(512), 0, stream>>>(ze, cb, ws_f, cbs8,
                                                     ws_u + 1024, ws_f + 2048, out);
        vq_fin<<<dim3(1), dim3(256), 0, stream>>>(ws_f + 2048, ws_u + 1024, out, 512);
    } else {
        vq_main_fb<<<dim3(1024), dim3(512), 0, stream>>>(ze, cb, ws_f, ws_u + 1024,
                                                         ws_f + 2048, out);
        vq_fin<<<dim3(1), dim3(256), 0, stream>>>(ws_f + 2048, ws_u + 1024, out, 1024);
    }
}